// Round 6
// baseline (196.695 us; speedup 1.0000x reference)
//
#include <hip/hip_runtime.h>
#include <math.h>

#define B_  8
#define N_  1024
#define H_  512
#define NH_ 8
#define DK_ 64
#define M_  (B_ * N_)   // 8192

typedef __attribute__((ext_vector_type(4))) float f32x4;
typedef __attribute__((ext_vector_type(8))) short bf16x8;

__device__ __forceinline__ unsigned short f2bf(float f) {
    unsigned int u = __float_as_uint(f);
    u = (u + 0x7fffu + ((u >> 16) & 1u)) >> 16;   // RNE
    return (unsigned short)u;
}

__device__ __forceinline__ unsigned int pk2bf(float a, float b) {
    return (unsigned int)f2bf(a) | ((unsigned int)f2bf(b) << 16);
}

__device__ __forceinline__ float bf2f(unsigned short s) {
    return __uint_as_float(((unsigned int)s) << 16);
}

__device__ __forceinline__ float fexp2(float x) {
#if __has_builtin(__builtin_amdgcn_exp2f)
    return __builtin_amdgcn_exp2f(x);
#else
    return exp2f(x);
#endif
}

__device__ __forceinline__ void gload16(const unsigned short* g, unsigned short* l) {
    __builtin_amdgcn_global_load_lds(
        (const __attribute__((address_space(1))) void*)g,
        (__attribute__((address_space(3))) void*)l, 16, 0, 0);
}

// ---------------------------------------------------------------------------
// Fused prep: fp32->bf16 convert of x/Wq(pre-scaled)/Wk/Wv/Wg  +  adj bitmask
// pack. r17: coarsened grid 13568 -> 4736 blocks. Convert: 32 B/thread
// (2 x float4 -> one uint4 of 8 bf16). Pack: 4 rows/block (1 row/wave,
// 16 ballots). Segments: x 2048 | Wq 128 | Wk 128 | Wv 128 | Wg 256 |
// pack 2048.
// ---------------------------------------------------------------------------
__global__ __launch_bounds__(256) void prep_k(const float* __restrict__ x,
                                              const float* __restrict__ Wq,
                                              const float* __restrict__ Wk,
                                              const float* __restrict__ Wv,
                                              const float* __restrict__ Wg,
                                              const int*   __restrict__ adj,
                                              unsigned short* __restrict__ xb,
                                              unsigned short* __restrict__ wqb,
                                              unsigned short* __restrict__ wkb,
                                              unsigned short* __restrict__ wvb,
                                              unsigned short* __restrict__ wgb,
                                              unsigned long long* __restrict__ mb)
{
    int id = blockIdx.x;
    if (id >= 2688) {   // pack segment: 4 rows per block, 1 row per wave
        int wv   = threadIdx.x >> 6;
        int lane = threadIdx.x & 63;
        int row  = (id - 2688) * 4 + wv;       // b*N + q, 0..8191
        const int* arow = &adj[(size_t)row * N_];
        #pragma unroll
        for (int kt = 0; kt < 16; ++kt) {
            unsigned long long m = __ballot(arow[kt * 64 + lane] != 0);
            if (lane == 0) mb[(size_t)row * 16 + kt] = m;
        }
        return;
    }
    const float* src; unsigned short* dst; int off; float scale = 1.0f;
    if (id < 2048)      { src = x;  dst = xb;  off = id; }
    else if (id < 2176) { src = Wq; dst = wqb; off = id - 2048; scale = 0.18033688011112042f; } // 0.125*log2(e)
    else if (id < 2304) { src = Wk; dst = wkb; off = id - 2176; }
    else if (id < 2432) { src = Wv; dst = wvb; off = id - 2304; }
    else                { src = Wg; dst = wgb; off = id - 2432; }
    size_t i = (size_t)off * 2048 + threadIdx.x * 8;
    float4 v0 = *(const float4*)&src[i];
    float4 v1 = *(const float4*)&src[i + 4];
    uint4 u;
    u.x = pk2bf(v0.x * scale, v0.y * scale);
    u.y = pk2bf(v0.z * scale, v0.w * scale);
    u.z = pk2bf(v1.x * scale, v1.y * scale);
    u.w = pk2bf(v1.z * scale, v1.w * scale);
    *(uint4*)&dst[i] = u;
}

// ---------------------------------------------------------------------------
// Fused QKV projection, BK=32, triple-buffered 2-ahead prefetch with counted
// vmcnt(4) + raw s_barrier. w=0/1 -> qk halves, w=2 -> Vt via LDS transpose.
// 128x128 tile, 4 waves 2x2. grid (64, 12) = 768 blocks = 3/CU (48 KB LDS).
// ---------------------------------------------------------------------------
__global__ __launch_bounds__(256, 3) void proj_k(const unsigned short* __restrict__ xb,
                                                 const unsigned short* __restrict__ Wqb,
                                                 const unsigned short* __restrict__ Wkb,
                                                 const unsigned short* __restrict__ Wvb,
                                                 unsigned short* __restrict__ qk,
                                                 unsigned short* __restrict__ vt)
{
    // 3 bufs x (A 4096 + B 4096 shorts) = 24576 shorts = 49152 B.
    // Epilogues reuse as Ts (needs 34816 B).
    __shared__ __align__(16) unsigned short SMEM[24576];

    const int tid = threadIdx.x;
    const int lane = tid & 63, wv = tid >> 6;
    const int ln = lane & 15, quad = lane >> 4;
    const int wm = wv >> 1, wn = wv & 1;
    const int row0 = blockIdx.x * 128;
    const int w    = blockIdx.y >> 2;
    const int col0 = (blockIdx.y & 3) * 128;
    const unsigned short* W = (w == 0) ? Wqb : ((w == 1) ? Wkb : Wvb);
    f32x4 acc[4][4] = {};

    auto issue = [&](int t, int bi) {
        int kt = t * 32;
        #pragma unroll
        for (int i = 0; i < 2; ++i) {
            int c = tid + i * 256;          // 0..511
            int c4 = c >> 7, row = c & 127;
            gload16(&xb[(size_t)(row0 + row) * H_ + kt + c4 * 8], &SMEM[bi * 8192 + c * 8]);
            gload16(&W [(size_t)(col0 + row) * H_ + kt + c4 * 8], &SMEM[bi * 8192 + 4096 + c * 8]);
        }
    };

    issue(0, 0);
    issue(1, 1);
    for (int t = 0; t < 16; ++t) {
        if (t < 15) { asm volatile("s_waitcnt vmcnt(4)" ::: "memory"); }
        else        { asm volatile("s_waitcnt vmcnt(0)" ::: "memory"); }
        __builtin_amdgcn_s_barrier();        // buffer t%3 ready for all waves
        __builtin_amdgcn_sched_barrier(0);
        if (t < 14) issue(t + 2, (t + 2) % 3);
        const unsigned short* Ac = &SMEM[(t % 3) * 8192];
        const unsigned short* Bc = Ac + 4096;
        bf16x8 af[4], bf[4];
        #pragma unroll
        for (int u = 0; u < 4; ++u) {
            af[u] = *(const bf16x8*)&Ac[(quad * 128 + wm * 64 + u * 16 + ln) * 8];
            bf[u] = *(const bf16x8*)&Bc[(quad * 128 + wn * 64 + u * 16 + ln) * 8];
        }
        #pragma unroll
        for (int mt = 0; mt < 4; ++mt)
            #pragma unroll
            for (int nt = 0; nt < 4; ++nt)
                acc[mt][nt] = __builtin_amdgcn_mfma_f32_16x16x32_bf16(af[mt], bf[nt], acc[mt][nt], 0, 0, 0);
    }

    if (w < 2) {
        // q/k: LDS-stage m-major [128][136] -> coalesced uint4 stores.
        __syncthreads();                     // all K-loop LDS reads done
        unsigned short* Ts = SMEM;
        #pragma unroll
        for (int mt = 0; mt < 4; ++mt)
            #pragma unroll
            for (int nt = 0; nt < 4; ++nt)
                #pragma unroll
                for (int r = 0; r < 4; ++r) {
                    int m_local = wm * 64 + mt * 16 + quad * 4 + r;
                    int c_local = wn * 64 + nt * 16 + ln;
                    Ts[m_local * 136 + c_local] = f2bf(acc[mt][nt][r]);
                }
        __syncthreads();
        #pragma unroll
        for (int j = 0; j < 8; ++j) {
            int m = j * 16 + (tid >> 4);              // 0..127
            int c = (tid & 15) * 8;                   // 0..120
            uint4 u = *(const uint4*)&Ts[m * 136 + c];
            *(uint4*)&qk[(size_t)(row0 + m) * (2 * H_) + w * H_ + col0 + c] = u;
        }
    } else {
        // V: LDS transpose -> coalesced vt stores.
        // Ts[c_local][n_local], stride 136 shorts (272 B, 16-B aligned rows).
        __syncthreads();                     // all K-loop LDS reads done
        unsigned short* Ts = SMEM;
        #pragma unroll
        for (int mt = 0; mt < 4; ++mt)
            #pragma unroll
            for (int nt = 0; nt < 4; ++nt) {
                int c_local = wn * 64 + nt * 16 + ln;
                int n_local = wm * 64 + mt * 16 + quad * 4;
                ushort4 u = make_ushort4(f2bf(acc[mt][nt][0]), f2bf(acc[mt][nt][1]),
                                         f2bf(acc[mt][nt][2]), f2bf(acc[mt][nt][3]));
                *(ushort4*)&Ts[c_local * 136 + n_local] = u;
            }
        __syncthreads();
        const int bb = row0 >> 10, n_base = row0 & (N_ - 1);
        #pragma unroll
        for (int j = 0; j < 8; ++j) {
            int c_local = (tid >> 4) + j * 16;       // 0..127
            int nc = (tid & 15) * 8;                 // 0..120
            int cg = col0 + c_local;
            int head = cg >> 6, d = cg & 63;
            uint4 u = *(const uint4*)&Ts[c_local * 136 + nc];
            *(uint4*)&vt[((size_t)(bb * NH_ + head) * DK_ + d) * N_ + n_base + nc] = u;
        }
    }
}

// ---------------------------------------------------------------------------
// Flash attention, S^T formulation. 512 threads / 8 waves per block, one 16-q
// group per wave. Triple-buffered K/V, 2-ahead prefetch, exact counted vmcnt:
//   even t: vmcnt(2) (drains tile t staged loads + its mask pair)
//   odd  t: vmcnt(3) (drains tile t staged loads exactly)
//   t=15 : vmcnt(0)
// Masks pair-loaded (16 B = 2 tiles/row) via global_load_lds by lanes<16 of
// every wave. exp2 softmax (Q pre-scaled by 0.125*log2e), psum via ones-MFMA,
// setprio around MFMA clusters. grid 512 = 2 blocks/CU (70 KB LDS).
// ---------------------------------------------------------------------------
__global__ __launch_bounds__(512, 4) void attn_k(const unsigned short* __restrict__ qk,
                                                 const unsigned short* __restrict__ Vt,
                                                 const unsigned long long* __restrict__ Mb,
                                                 unsigned short* __restrict__ Cmb)
{
    const int bh   = blockIdx.x & 63;            // same head group -> same XCD
    const int qt   = blockIdx.x >> 6;            // 0..7
    const int b    = bh >> 3;
    const int head = bh & 7;

    __shared__ __align__(16) unsigned short Ks[3][4096];   // [c8][row][8]
    __shared__ __align__(16) unsigned short Vs[3][4096];
    __shared__ __align__(16) unsigned short Ps[8][16][72]; // per-wave [q=ln][key]
    __shared__ __align__(16) unsigned long long Ms[2][8][16][2]; // [pairbuf][wave][row][t&1]

    const int tid = threadIdx.x;
    const int lane = tid & 63, wv = tid >> 6;    // wv 0..7
    const int ln = lane & 15, quad = lane >> 4;
    const int q0 = qt * 128 + wv * 16 + ln;

    const unsigned short* Kbase = qk + H_ + head * DK_;
    const unsigned short* Vbase = Vt + (size_t)(b * NH_ + head) * DK_ * N_;

    bf16x8 bq[2];
    #pragma unroll
    for (int kk = 0; kk < 2; ++kk)
        bq[kk] = *(const bf16x8*)&qk[(size_t)(b * N_ + q0) * (2 * H_) + head * DK_ + kk * 32 + quad * 8];

    bf16x8 ones;
    #pragma unroll
    for (int j = 0; j < 8; ++j) ones[j] = (short)0x3F80;   // bf16 1.0

    f32x4 o[4] = {};
    f32x4 osum = {};

    // 1 K-load + 1 V-load per thread per tile (512 threads cover 8 c8 x 64 rows)
    auto issue = [&](int t, int bi) {
        gload16(&Kbase[(size_t)(b * N_ + t * 64 + lane) * (2 * H_) + wv * 8], &Ks[bi][tid * 8]);
        gload16(&Vbase[(size_t)lane * N_ + t * 64 + wv * 8], &Vs[bi][tid * 8]);
    };
    // mask pair (2tp, 2tp+1): each wave's lanes<16 load its own 16 rows (16 B each)
    auto mask_issue = [&](int tp, int pb) {
        if (lane < 16) {
            const unsigned long long* src =
                &Mb[(size_t)(b * N_ + qt * 128 + wv * 16 + lane) * 16 + tp * 2];
            __builtin_amdgcn_global_load_lds(
                (const __attribute__((address_space(1))) void*)src,
                (__attribute__((address_space(3))) void*)&Ms[pb][wv][lane][0], 16, 0, 0);
        }
    };

    auto compute = [&](int t, int tp) {
        const unsigned short* Kc = Ks[t % 3];
        const unsigned short* Vc = Vs[t % 3];
        unsigned long long mq = Ms[tp & 1][wv][ln][t & 1];

        f32x4 s[4] = {};
        __builtin_amdgcn_s_setprio(1);
        #pragma unroll
        for (int kk = 0; kk < 2; ++kk)
            #pragma unroll
            for (int nt = 0; nt < 4; ++nt) {
                bf16x8 ka = *(const bf16x8*)&Kc[((kk * 4 + quad) * 64 + nt * 16 + ln) * 8];
                s[nt] = __builtin_amdgcn_mfma_f32_16x16x32_bf16(ka, bq[kk], s[nt], 0, 0, 0);
            }
        __builtin_amdgcn_s_setprio(0);

        unsigned long long sh = mq >> (quad * 4);
        #pragma unroll
        for (int nt = 0; nt < 4; ++nt) {
            unsigned int bn = (unsigned int)(sh >> (nt * 16)) & 0xFu;
            float p[4];
            #pragma unroll
            for (int r = 0; r < 4; ++r) {
                float e = fexp2(s[nt][r]);
                p[r] = (bn & (1u << r)) ? e : 0.f;
            }
            unsigned int d0 = __builtin_amdgcn_perm(__float_as_uint(p[1]), __float_as_uint(p[0]), 0x07060302u);
            unsigned int d1 = __builtin_amdgcn_perm(__float_as_uint(p[3]), __float_as_uint(p[2]), 0x07060302u);
            *(uint2*)&Ps[wv][ln][nt * 16 + quad * 4] = make_uint2(d0, d1);
        }

        bf16x8 pb[2];
        #pragma unroll
        for (int kk = 0; kk < 2; ++kk)
            pb[kk] = *(const bf16x8*)&Ps[wv][ln][kk * 32 + quad * 8];

        __builtin_amdgcn_s_setprio(1);
        #pragma unroll
        for (int kk = 0; kk < 2; ++kk) {
            #pragma unroll
            for (int dt = 0; dt < 4; ++dt) {
                bf16x8 va = *(const bf16x8*)&Vc[((kk * 4 + quad) * 64 + dt * 16 + ln) * 8];
                o[dt] = __builtin_amdgcn_mfma_f32_16x16x32_bf16(va, pb[kk], o[dt], 0, 0, 0);
            }
            osum = __builtin_amdgcn_mfma_f32_16x16x32_bf16(ones, pb[kk], osum, 0, 0, 0);
        }
        __builtin_amdgcn_s_setprio(0);
    };

    // Prologue: st0(2), mask pair(0,1)(1), st1(2) -> 5 outstanding per wave.
    issue(0, 0);
    mask_issue(0, 0);
    issue(1, 1);

    for (int tp = 0; tp < 8; ++tp) {
        // even t = 2*tp: drain [st_t(2) + mask_pair(1)]
        {
            const int t = 2 * tp;
            asm volatile("s_waitcnt vmcnt(2)" ::: "memory");
            __builtin_amdgcn_s_barrier();
            __builtin_amdgcn_sched_barrier(0);
            if (t < 14) { issue(t + 2, (t + 2) % 3); mask_issue(tp + 1, (tp + 1) & 1); }
            compute(t, tp);
        }
        // odd t = 2*tp+1: drain st_t(2) exactly (3 newer remain in steady state)
        {
            const int t = 2 * tp + 1;
            if (tp < 7) { asm volatile("s_waitcnt vmcnt(3)" ::: "memory"); }
            else        { asm volatile("s_waitcnt vmcnt(0)" ::: "memory"); }
            __builtin_amdgcn_s_barrier();
            __builtin_amdgcn_sched_barrier(0);
            if (t < 14) issue(t + 2, (t + 2) % 3);
            compute(t, tp);
        }
    }

    float inv = 1.f / osum[0];
    #pragma unroll
    for (int dt = 0; dt < 4; ++dt) {
        ushort4 u = make_ushort4(f2bf(o[dt][0] * inv), f2bf(o[dt][1] * inv),
                                 f2bf(o[dt][2] * inv), f2bf(o[dt][3] * inv));
        *(ushort4*)&Cmb[(size_t)(b * N_ + q0) * H_ + head * DK_ + dt * 16 + quad * 4] = u;
    }
}

// ---------------------------------------------------------------------------
// Gate GEMM (K=1024, A=[cmb|xb] bf16), BK=64 double-buffered pipelined,
// + sigmoid + residual (bf16 x), fp32 out. 128x64 tile, grid (64,8).
// 2-buf 49152 B -> 3 blocks/CU, 12 waves/CU. Epilogue LDS-staged fp32
// [128][68] with vectorized loads/stores.
// ---------------------------------------------------------------------------
__global__ __launch_bounds__(256, 3) void gate_k(const unsigned short* __restrict__ cmb,
                                                 const unsigned short* __restrict__ xb,
                                                 const unsigned short* __restrict__ Wgb,
                                                 const float* __restrict__ bgp,
                                                 float* __restrict__ out)
{
    __shared__ __align__(16) unsigned short GSM[24576];   // 49152 B
    unsigned short* As = GSM;            // [bi*8192 + idx], 16 KB each buf
    unsigned short* Bs = GSM + 16384;    // [bi*4096 + idx],  8 KB each buf
    const int tid = threadIdx.x;
    const int lane = tid & 63, wv = tid >> 6;
    const int ln = lane & 15, quad = lane >> 4;
    const int wm = wv >> 1, wn = wv & 1;
    const int row0 = blockIdx.x * 128;
    const int col0 = blockIdx.y * 64;
    f32x4 acc[4][2] = {};

    auto issue = [&](int t, int bi) {
        const unsigned short* Asrc = (t < 8) ? cmb : xb;
        int ko = (t * 64) & (H_ - 1);
        #pragma unroll
        for (int i = 0; i < 4; ++i) {
            int c = tid + i * 256;            // 0..1023
            int c8 = c >> 7, row = c & 127;
            gload16(&Asrc[(size_t)(row0 + row) * H_ + ko + c8 * 8], &As[bi * 8192 + c * 8]);
        }
        #pragma unroll
        for (int i = 0; i < 2; ++i) {
            int c = tid + i * 256;            // 0..511
            int c8 = c >> 6, row = c & 63;
            gload16(&Wgb[(size_t)(col0 + row) * (2 * H_) + t * 64 + c8 * 8], &Bs[bi * 4096 + c * 8]);
        }
    };

    issue(0, 0);
    for (int t = 0; t < 16; ++t) {
        __syncthreads();
        if (t < 15) issue(t + 1, (t + 1) & 1);
        const unsigned short* Ac = &As[(t & 1) * 8192];
        const unsigned short* Bc = &Bs[(t & 1) * 4096];
        #pragma unroll
        for (int kk = 0; kk < 2; ++kk) {
            bf16x8 af[4], bf[2];
            #pragma unroll
            for (int u = 0; u < 4; ++u)
                af[u] = *(const bf16x8*)&Ac[((kk * 4 + quad) * 128 + wm * 64 + u * 16 + ln) * 8];
            #pragma unroll
            for (int u = 0; u < 2; ++u)
                bf[u] = *(const bf16x8*)&Bc[((kk * 4 + quad) * 64 + wn * 32 + u * 16 + ln) * 8];
            #pragma unroll
            for (int mt = 0; mt < 4; ++mt)
                #pragma unroll
                for (int nt = 0; nt < 2; ++nt)
                    acc[mt][nt] = __builtin_amdgcn_mfma_f32_16x16x32_bf16(af[mt], bf[nt], acc[mt][nt], 0, 0, 0);
        }
    }

    // Epilogue: stage acc into fp32 LDS [m:128][c:64 pad->68], then process
    // the tile in coalesced layout (lane ln -> 4 consecutive c).
    __syncthreads();                          // all K-loop LDS reads done
    float* Tsf = (float*)GSM;                 // 128*68*4 = 34816 B <= 49152
    #pragma unroll
    for (int mt = 0; mt < 4; ++mt)
        #pragma unroll
        for (int nt = 0; nt < 2; ++nt)
            #pragma unroll
            for (int r = 0; r < 4; ++r) {
                int m_local = wm * 64 + mt * 16 + quad * 4 + r;
                int c_local = wn * 32 + nt * 16 + ln;
                Tsf[m_local * 68 + c_local] = acc[mt][nt][r];
            }
    __syncthreads();

    const int cl = (tid & 15) * 4;            // 0..60
    const float4 bg4 = *(const float4*)&bgp[col0 + cl];
    #pragma unroll
    for (int j = 0; j < 8; ++j) {
        int m = j * 16 + (tid >> 4);          // 0..127
        f32x4 a = *(const f32x4*)&Tsf[m * 68 + cl];
        ushort4 xv4 = *(const ushort4*)&xb [(size_t)(row0 + m) * H_ + col0 + cl];
        ushort4 cv4 = *(const ushort4*)&cmb[(size_t)(row0 + m) * H_ + col0 + cl];
        float4 o;
        {
            float g0 = 1.f / (1.f + __expf(-(a[0] + bg4.x)));
            float g1 = 1.f / (1.f + __expf(-(a[1] + bg4.y)));
            float g2 = 1.f / (1.f + __expf(-(a[2] + bg4.z)));
            float g3 = 1.f / (1.f + __expf(-(a[3] + bg4.w)));
            o.x = g0 * bf2f(xv4.x) + (1.f - g0) * bf2f(cv4.x);
            o.y = g1 * bf2f(xv4.y) + (1.f - g1) * bf2f(cv4.y);
            o.z = g2 * bf2f(xv4.z) + (1.f - g2) * bf2f(cv4.z);
            o.w = g3 * bf2f(xv4.w) + (1.f - g3) * bf2f(cv4.w);
        }
        *(float4*)&out[(size_t)(row0 + m) * H_ + col0 + cl] = o;
    }
}

// ---------------------------------------------------------------------------
extern "C" void kernel_launch(void* const* d_in, const int* in_sizes, int n_in,
                              void* d_out, int out_size, void* d_ws, size_t ws_size,
                              hipStream_t stream)
{
    const float* x   = (const float*)d_in[0];
    const int*   adj = (const int*)  d_in[1];
    const float* Wq  = (const float*)d_in[2];
    const float* Wk  = (const float*)d_in[3];
    const float* Wv  = (const float*)d_in[4];
    const float* Wg  = (const float*)d_in[5];
    const float* bg  = (const float*)d_in[6];
    float* out = (float*)d_out;

    unsigned short* xb  = (unsigned short*)d_ws;                      // 8 MB
    unsigned short* wqb = xb  + (size_t)M_ * H_;                      // 512 KB
    unsigned short* wkb = wqb + (size_t)H_ * H_;
    unsigned short* wvb = wkb + (size_t)H_ * H_;
    unsigned short* wgb = wvb + (size_t)H_ * H_;                      // 1 MB
    unsigned short* qk  = wgb + (size_t)H_ * 2 * H_;                  // 16 MB
    unsigned short* vt  = qk  + (size_t)M_ * 2 * H_;                  // 8 MB
    unsigned short* cmb = vt  + (size_t)M_ * H_;                      // 8 MB
    unsigned long long* mb = (unsigned long long*)(cmb + (size_t)M_ * H_);  // 1 MB

    prep_k<<<2688 + 2048, 256, 0, stream>>>(x, Wq, Wk, Wv, Wg, adj,
                                            xb, wqb, wkb, wvb, wgb, mb);

    proj_k<<<dim3(M_ / 128, 12), 256, 0, stream>>>(xb, wqb, wkb, wvb, qk, vt);

    attn_k<<<B_ * NH_ * (N_ / 128), 512, 0, stream>>>(qk, vt, mb, cmb);

    gate_k<<<dim3(M_ / 128, H_ / 64), 256, 0, stream>>>(cmb, xb, wgb, bg, out);
}

// Round 8
// 193.776 us; speedup vs baseline: 1.0151x; 1.0151x over previous
//
#include <hip/hip_runtime.h>
#include <math.h>

#define B_  8
#define N_  1024
#define H_  512
#define NH_ 8
#define DK_ 64
#define M_  (B_ * N_)   // 8192

typedef __attribute__((ext_vector_type(4))) float f32x4;
typedef __attribute__((ext_vector_type(8))) short bf16x8;

__device__ __forceinline__ unsigned short f2bf(float f) {
    unsigned int u = __float_as_uint(f);
    u = (u + 0x7fffu + ((u >> 16) & 1u)) >> 16;   // RNE
    return (unsigned short)u;
}

__device__ __forceinline__ float bf2f(unsigned short s) {
    return __uint_as_float(((unsigned int)s) << 16);
}

__device__ __forceinline__ float fexp2(float x) {
#if __has_builtin(__builtin_amdgcn_exp2f)
    return __builtin_amdgcn_exp2f(x);
#else
    return exp2f(x);
#endif
}

__device__ __forceinline__ void gload16(const unsigned short* g, unsigned short* l) {
    __builtin_amdgcn_global_load_lds(
        (const __attribute__((address_space(1))) void*)g,
        (__attribute__((address_space(3))) void*)l, 16, 0, 0);
}

// ---------------------------------------------------------------------------
// Fused prep: fp32->bf16 convert of x/Wq(pre-scaled)/Wk/Wv/Wg  +  adj bitmask
// pack. Segments (blocks): x 4096 | Wq 256 | Wk 256 | Wv 256 | Wg 512 |
// pack 8192 (one q-row per block; wave wv does words wv*4..wv*4+3).
// (r17 coarsening regressed +2.6 us: longer per-wave ballot/load chains with
// less TLP — this is the r16-measured fine-grained form.)
// ---------------------------------------------------------------------------
__global__ __launch_bounds__(256) void prep_k(const float* __restrict__ x,
                                              const float* __restrict__ Wq,
                                              const float* __restrict__ Wk,
                                              const float* __restrict__ Wv,
                                              const float* __restrict__ Wg,
                                              const int*   __restrict__ adj,
                                              unsigned short* __restrict__ xb,
                                              unsigned short* __restrict__ wqb,
                                              unsigned short* __restrict__ wkb,
                                              unsigned short* __restrict__ wvb,
                                              unsigned short* __restrict__ wgb,
                                              unsigned long long* __restrict__ mb)
{
    int id = blockIdx.x;
    if (id >= 5376) {   // pack segment: one (b,q) row per block
        int row  = id - 5376;                  // b*N + q
        int wv   = threadIdx.x >> 6;
        int lane = threadIdx.x & 63;
        const int* arow = &adj[(size_t)row * N_];
        #pragma unroll
        for (int j = 0; j < 4; ++j) {
            int kt = wv * 4 + j;
            int val = arow[kt * 64 + lane];
            unsigned long long m = __ballot(val != 0);
            if (lane == 0) mb[(size_t)row * 16 + kt] = m;
        }
        return;
    }
    const float* src; unsigned short* dst; int off; float scale = 1.0f;
    if (id < 4096)      { src = x;  dst = xb;  off = id; }
    else if (id < 4352) { src = Wq; dst = wqb; off = id - 4096; scale = 0.18033688011112042f; } // 0.125*log2(e)
    else if (id < 4608) { src = Wk; dst = wkb; off = id - 4352; }
    else if (id < 4864) { src = Wv; dst = wvb; off = id - 4608; }
    else                { src = Wg; dst = wgb; off = id - 4864; }
    size_t i = (size_t)off * 1024 + threadIdx.x * 4;
    float4 v = *(const float4*)&src[i];
    *(ushort4*)&dst[i] = make_ushort4(f2bf(v.x * scale), f2bf(v.y * scale),
                                      f2bf(v.z * scale), f2bf(v.w * scale));
}

// ---------------------------------------------------------------------------
// Fused QKV projection, BK=32, triple-buffered 2-ahead prefetch with counted
// vmcnt(4) + raw s_barrier. w=0/1 -> qk halves, w=2 -> Vt via LDS transpose.
// 128x128 tile, 4 waves 2x2. grid (64, 12) = 768 blocks = 3/CU (48 KB LDS).
// ---------------------------------------------------------------------------
__global__ __launch_bounds__(256, 3) void proj_k(const unsigned short* __restrict__ xb,
                                                 const unsigned short* __restrict__ Wqb,
                                                 const unsigned short* __restrict__ Wkb,
                                                 const unsigned short* __restrict__ Wvb,
                                                 unsigned short* __restrict__ qk,
                                                 unsigned short* __restrict__ vt)
{
    // 3 bufs x (A 4096 + B 4096 shorts) = 24576 shorts = 49152 B.
    // Epilogues reuse as Ts (needs 34816 B).
    __shared__ __align__(16) unsigned short SMEM[24576];

    const int tid = threadIdx.x;
    const int lane = tid & 63, wv = tid >> 6;
    const int ln = lane & 15, quad = lane >> 4;
    const int wm = wv >> 1, wn = wv & 1;
    const int row0 = blockIdx.x * 128;
    const int w    = blockIdx.y >> 2;
    const int col0 = (blockIdx.y & 3) * 128;
    const unsigned short* W = (w == 0) ? Wqb : ((w == 1) ? Wkb : Wvb);
    f32x4 acc[4][4] = {};

    auto issue = [&](int t, int bi) {
        int kt = t * 32;
        #pragma unroll
        for (int i = 0; i < 2; ++i) {
            int c = tid + i * 256;          // 0..511
            int c4 = c >> 7, row = c & 127;
            gload16(&xb[(size_t)(row0 + row) * H_ + kt + c4 * 8], &SMEM[bi * 8192 + c * 8]);
            gload16(&W [(size_t)(col0 + row) * H_ + kt + c4 * 8], &SMEM[bi * 8192 + 4096 + c * 8]);
        }
    };

    issue(0, 0);
    issue(1, 1);
    for (int t = 0; t < 16; ++t) {
        if (t < 15) { asm volatile("s_waitcnt vmcnt(4)" ::: "memory"); }
        else        { asm volatile("s_waitcnt vmcnt(0)" ::: "memory"); }
        __builtin_amdgcn_s_barrier();        // buffer t%3 ready for all waves
        __builtin_amdgcn_sched_barrier(0);
        if (t < 14) issue(t + 2, (t + 2) % 3);
        const unsigned short* Ac = &SMEM[(t % 3) * 8192];
        const unsigned short* Bc = Ac + 4096;
        bf16x8 af[4], bf[4];
        #pragma unroll
        for (int u = 0; u < 4; ++u) {
            af[u] = *(const bf16x8*)&Ac[(quad * 128 + wm * 64 + u * 16 + ln) * 8];
            bf[u] = *(const bf16x8*)&Bc[(quad * 128 + wn * 64 + u * 16 + ln) * 8];
        }
        #pragma unroll
        for (int mt = 0; mt < 4; ++mt)
            #pragma unroll
            for (int nt = 0; nt < 4; ++nt)
                acc[mt][nt] = __builtin_amdgcn_mfma_f32_16x16x32_bf16(af[mt], bf[nt], acc[mt][nt], 0, 0, 0);
    }

    if (w < 2) {
        // q/k: LDS-stage m-major [128][136] -> coalesced uint4 stores.
        __syncthreads();                     // all K-loop LDS reads done
        unsigned short* Ts = SMEM;
        #pragma unroll
        for (int mt = 0; mt < 4; ++mt)
            #pragma unroll
            for (int nt = 0; nt < 4; ++nt)
                #pragma unroll
                for (int r = 0; r < 4; ++r) {
                    int m_local = wm * 64 + mt * 16 + quad * 4 + r;
                    int c_local = wn * 64 + nt * 16 + ln;
                    Ts[m_local * 136 + c_local] = f2bf(acc[mt][nt][r]);
                }
        __syncthreads();
        #pragma unroll
        for (int j = 0; j < 8; ++j) {
            int m = j * 16 + (tid >> 4);              // 0..127
            int c = (tid & 15) * 8;                   // 0..120
            uint4 u = *(const uint4*)&Ts[m * 136 + c];
            *(uint4*)&qk[(size_t)(row0 + m) * (2 * H_) + w * H_ + col0 + c] = u;
        }
    } else {
        // V: LDS transpose -> coalesced vt stores.
        // Ts[c_local][n_local], stride 136 shorts (272 B, 16-B aligned rows).
        __syncthreads();                     // all K-loop LDS reads done
        unsigned short* Ts = SMEM;
        #pragma unroll
        for (int mt = 0; mt < 4; ++mt)
            #pragma unroll
            for (int nt = 0; nt < 4; ++nt) {
                int c_local = wn * 64 + nt * 16 + ln;
                int n_local = wm * 64 + mt * 16 + quad * 4;
                ushort4 u = make_ushort4(f2bf(acc[mt][nt][0]), f2bf(acc[mt][nt][1]),
                                         f2bf(acc[mt][nt][2]), f2bf(acc[mt][nt][3]));
                *(ushort4*)&Ts[c_local * 136 + n_local] = u;
            }
        __syncthreads();
        const int bb = row0 >> 10, n_base = row0 & (N_ - 1);
        #pragma unroll
        for (int j = 0; j < 8; ++j) {
            int c_local = (tid >> 4) + j * 16;       // 0..127
            int nc = (tid & 15) * 8;                 // 0..120
            int cg = col0 + c_local;
            int head = cg >> 6, d = cg & 63;
            uint4 u = *(const uint4*)&Ts[c_local * 136 + nc];
            *(uint4*)&vt[((size_t)(bb * NH_ + head) * DK_ + d) * N_ + n_base + nc] = u;
        }
    }
}

// ---------------------------------------------------------------------------
// Flash attention, S^T formulation. 512 threads / 8 waves per block, one 16-q
// group per wave. Triple-buffered K/V, 2-ahead prefetch, exact counted vmcnt:
//   even t: vmcnt(2) (drains tile t staged loads + its mask pair)
//   odd  t: vmcnt(3) (drains tile t staged loads exactly)
//   t=15 : vmcnt(0)
// Masks pair-loaded (16 B = 2 tiles/row) via global_load_lds by lanes<16 of
// every wave. exp2 softmax (Q pre-scaled by 0.125*log2e), psum via ones-MFMA,
// setprio around MFMA clusters. grid 512 = 2 blocks/CU (70 KB LDS).
// ---------------------------------------------------------------------------
__global__ __launch_bounds__(512, 4) void attn_k(const unsigned short* __restrict__ qk,
                                                 const unsigned short* __restrict__ Vt,
                                                 const unsigned long long* __restrict__ Mb,
                                                 unsigned short* __restrict__ Cmb)
{
    const int bh   = blockIdx.x & 63;            // same head group -> same XCD
    const int qt   = blockIdx.x >> 6;            // 0..7
    const int b    = bh >> 3;
    const int head = bh & 7;

    __shared__ __align__(16) unsigned short Ks[3][4096];   // [c8][row][8]
    __shared__ __align__(16) unsigned short Vs[3][4096];
    __shared__ __align__(16) unsigned short Ps[8][16][72]; // per-wave [q=ln][key]
    __shared__ __align__(16) unsigned long long Ms[2][8][16][2]; // [pairbuf][wave][row][t&1]

    const int tid = threadIdx.x;
    const int lane = tid & 63, wv = tid >> 6;    // wv 0..7
    const int ln = lane & 15, quad = lane >> 4;
    const int q0 = qt * 128 + wv * 16 + ln;

    const unsigned short* Kbase = qk + H_ + head * DK_;
    const unsigned short* Vbase = Vt + (size_t)(b * NH_ + head) * DK_ * N_;

    bf16x8 bq[2];
    #pragma unroll
    for (int kk = 0; kk < 2; ++kk)
        bq[kk] = *(const bf16x8*)&qk[(size_t)(b * N_ + q0) * (2 * H_) + head * DK_ + kk * 32 + quad * 8];

    bf16x8 ones;
    #pragma unroll
    for (int j = 0; j < 8; ++j) ones[j] = (short)0x3F80;   // bf16 1.0

    f32x4 o[4] = {};
    f32x4 osum = {};

    // 1 K-load + 1 V-load per thread per tile (512 threads cover 8 c8 x 64 rows)
    auto issue = [&](int t, int bi) {
        gload16(&Kbase[(size_t)(b * N_ + t * 64 + lane) * (2 * H_) + wv * 8], &Ks[bi][tid * 8]);
        gload16(&Vbase[(size_t)lane * N_ + t * 64 + wv * 8], &Vs[bi][tid * 8]);
    };
    // mask pair (2tp, 2tp+1): each wave's lanes<16 load its own 16 rows (16 B each)
    auto mask_issue = [&](int tp, int pb) {
        if (lane < 16) {
            const unsigned long long* src =
                &Mb[(size_t)(b * N_ + qt * 128 + wv * 16 + lane) * 16 + tp * 2];
            __builtin_amdgcn_global_load_lds(
                (const __attribute__((address_space(1))) void*)src,
                (__attribute__((address_space(3))) void*)&Ms[pb][wv][lane][0], 16, 0, 0);
        }
    };

    auto compute = [&](int t, int tp) {
        const unsigned short* Kc = Ks[t % 3];
        const unsigned short* Vc = Vs[t % 3];
        unsigned long long mq = Ms[tp & 1][wv][ln][t & 1];

        f32x4 s[4] = {};
        __builtin_amdgcn_s_setprio(1);
        #pragma unroll
        for (int kk = 0; kk < 2; ++kk)
            #pragma unroll
            for (int nt = 0; nt < 4; ++nt) {
                bf16x8 ka = *(const bf16x8*)&Kc[((kk * 4 + quad) * 64 + nt * 16 + ln) * 8];
                s[nt] = __builtin_amdgcn_mfma_f32_16x16x32_bf16(ka, bq[kk], s[nt], 0, 0, 0);
            }
        __builtin_amdgcn_s_setprio(0);

        unsigned long long sh = mq >> (quad * 4);
        #pragma unroll
        for (int nt = 0; nt < 4; ++nt) {
            unsigned int bn = (unsigned int)(sh >> (nt * 16)) & 0xFu;
            float p[4];
            #pragma unroll
            for (int r = 0; r < 4; ++r) {
                float e = fexp2(s[nt][r]);
                p[r] = (bn & (1u << r)) ? e : 0.f;
            }
            unsigned int d0 = __builtin_amdgcn_perm(__float_as_uint(p[1]), __float_as_uint(p[0]), 0x07060302u);
            unsigned int d1 = __builtin_amdgcn_perm(__float_as_uint(p[3]), __float_as_uint(p[2]), 0x07060302u);
            *(uint2*)&Ps[wv][ln][nt * 16 + quad * 4] = make_uint2(d0, d1);
        }

        bf16x8 pb[2];
        #pragma unroll
        for (int kk = 0; kk < 2; ++kk)
            pb[kk] = *(const bf16x8*)&Ps[wv][ln][kk * 32 + quad * 8];

        __builtin_amdgcn_s_setprio(1);
        #pragma unroll
        for (int kk = 0; kk < 2; ++kk) {
            #pragma unroll
            for (int dt = 0; dt < 4; ++dt) {
                bf16x8 va = *(const bf16x8*)&Vc[((kk * 4 + quad) * 64 + dt * 16 + ln) * 8];
                o[dt] = __builtin_amdgcn_mfma_f32_16x16x32_bf16(va, pb[kk], o[dt], 0, 0, 0);
            }
            osum = __builtin_amdgcn_mfma_f32_16x16x32_bf16(ones, pb[kk], osum, 0, 0, 0);
        }
        __builtin_amdgcn_s_setprio(0);
    };

    // Prologue: st0(2), mask pair(0,1)(1), st1(2) -> 5 outstanding per wave.
    issue(0, 0);
    mask_issue(0, 0);
    issue(1, 1);

    for (int tp = 0; tp < 8; ++tp) {
        // even t = 2*tp: drain [st_t(2) + mask_pair(1)]
        {
            const int t = 2 * tp;
            asm volatile("s_waitcnt vmcnt(2)" ::: "memory");
            __builtin_amdgcn_s_barrier();
            __builtin_amdgcn_sched_barrier(0);
            if (t < 14) { issue(t + 2, (t + 2) % 3); mask_issue(tp + 1, (tp + 1) & 1); }
            compute(t, tp);
        }
        // odd t = 2*tp+1: drain st_t(2) exactly (3 newer remain in steady state)
        {
            const int t = 2 * tp + 1;
            if (tp < 7) { asm volatile("s_waitcnt vmcnt(3)" ::: "memory"); }
            else        { asm volatile("s_waitcnt vmcnt(0)" ::: "memory"); }
            __builtin_amdgcn_s_barrier();
            __builtin_amdgcn_sched_barrier(0);
            if (t < 14) issue(t + 2, (t + 2) % 3);
            compute(t, tp);
        }
    }

    float inv = 1.f / osum[0];
    #pragma unroll
    for (int dt = 0; dt < 4; ++dt) {
        ushort4 u = make_ushort4(f2bf(o[dt][0] * inv), f2bf(o[dt][1] * inv),
                                 f2bf(o[dt][2] * inv), f2bf(o[dt][3] * inv));
        *(ushort4*)&Cmb[(size_t)(b * N_ + q0) * H_ + head * DK_ + dt * 16 + quad * 4] = u;
    }
}

// ---------------------------------------------------------------------------
// Gate GEMM (K=1024, A=[cmb|xb] bf16), BK=64 double-buffered pipelined,
// + sigmoid + residual (bf16 x), fp32 out. 128x64 tile, grid (64,8).
// 2-buf 49152 B -> 3 blocks/CU, 12 waves/CU. Epilogue LDS-staged fp32
// [128][68] with vectorized loads/stores.
// ---------------------------------------------------------------------------
__global__ __launch_bounds__(256, 3) void gate_k(const unsigned short* __restrict__ cmb,
                                                 const unsigned short* __restrict__ xb,
                                                 const unsigned short* __restrict__ Wgb,
                                                 const float* __restrict__ bgp,
                                                 float* __restrict__ out)
{
    __shared__ __align__(16) unsigned short GSM[24576];   // 49152 B
    unsigned short* As = GSM;            // [bi*8192 + idx], 16 KB each buf
    unsigned short* Bs = GSM + 16384;    // [bi*4096 + idx],  8 KB each buf
    const int tid = threadIdx.x;
    const int lane = tid & 63, wv = tid >> 6;
    const int ln = lane & 15, quad = lane >> 4;
    const int wm = wv >> 1, wn = wv & 1;
    const int row0 = blockIdx.x * 128;
    const int col0 = blockIdx.y * 64;
    f32x4 acc[4][2] = {};

    auto issue = [&](int t, int bi) {
        const unsigned short* Asrc = (t < 8) ? cmb : xb;
        int ko = (t * 64) & (H_ - 1);
        #pragma unroll
        for (int i = 0; i < 4; ++i) {
            int c = tid + i * 256;            // 0..1023
            int c8 = c >> 7, row = c & 127;
            gload16(&Asrc[(size_t)(row0 + row) * H_ + ko + c8 * 8], &As[bi * 8192 + c * 8]);
        }
        #pragma unroll
        for (int i = 0; i < 2; ++i) {
            int c = tid + i * 256;            // 0..511
            int c8 = c >> 6, row = c & 63;
            gload16(&Wgb[(size_t)(col0 + row) * (2 * H_) + t * 64 + c8 * 8], &Bs[bi * 4096 + c * 8]);
        }
    };

    issue(0, 0);
    for (int t = 0; t < 16; ++t) {
        __syncthreads();
        if (t < 15) issue(t + 1, (t + 1) & 1);
        const unsigned short* Ac = &As[(t & 1) * 8192];
        const unsigned short* Bc = &Bs[(t & 1) * 4096];
        #pragma unroll
        for (int kk = 0; kk < 2; ++kk) {
            bf16x8 af[4], bf[2];
            #pragma unroll
            for (int u = 0; u < 4; ++u)
                af[u] = *(const bf16x8*)&Ac[((kk * 4 + quad) * 128 + wm * 64 + u * 16 + ln) * 8];
            #pragma unroll
            for (int u = 0; u < 2; ++u)
                bf[u] = *(const bf16x8*)&Bc[((kk * 4 + quad) * 64 + wn * 32 + u * 16 + ln) * 8];
            #pragma unroll
            for (int mt = 0; mt < 4; ++mt)
                #pragma unroll
                for (int nt = 0; nt < 2; ++nt)
                    acc[mt][nt] = __builtin_amdgcn_mfma_f32_16x16x32_bf16(af[mt], bf[nt], acc[mt][nt], 0, 0, 0);
        }
    }

    // Epilogue: stage acc into fp32 LDS [m:128][c:64 pad->68], then process
    // the tile in coalesced layout (lane ln -> 4 consecutive c).
    __syncthreads();                          // all K-loop LDS reads done
    float* Tsf = (float*)GSM;                 // 128*68*4 = 34816 B <= 49152
    #pragma unroll
    for (int mt = 0; mt < 4; ++mt)
        #pragma unroll
        for (int nt = 0; nt < 2; ++nt)
            #pragma unroll
            for (int r = 0; r < 4; ++r) {
                int m_local = wm * 64 + mt * 16 + quad * 4 + r;
                int c_local = wn * 32 + nt * 16 + ln;
                Tsf[m_local * 68 + c_local] = acc[mt][nt][r];
            }
    __syncthreads();

    const int cl = (tid & 15) * 4;            // 0..60
    const float4 bg4 = *(const float4*)&bgp[col0 + cl];
    #pragma unroll
    for (int j = 0; j < 8; ++j) {
        int m = j * 16 + (tid >> 4);          // 0..127
        f32x4 a = *(const f32x4*)&Tsf[m * 68 + cl];
        ushort4 xv4 = *(const ushort4*)&xb [(size_t)(row0 + m) * H_ + col0 + cl];
        ushort4 cv4 = *(const ushort4*)&cmb[(size_t)(row0 + m) * H_ + col0 + cl];
        float4 o;
        {
            float g0 = 1.f / (1.f + __expf(-(a[0] + bg4.x)));
            float g1 = 1.f / (1.f + __expf(-(a[1] + bg4.y)));
            float g2 = 1.f / (1.f + __expf(-(a[2] + bg4.z)));
            float g3 = 1.f / (1.f + __expf(-(a[3] + bg4.w)));
            o.x = g0 * bf2f(xv4.x) + (1.f - g0) * bf2f(cv4.x);
            o.y = g1 * bf2f(xv4.y) + (1.f - g1) * bf2f(cv4.y);
            o.z = g2 * bf2f(xv4.z) + (1.f - g2) * bf2f(cv4.z);
            o.w = g3 * bf2f(xv4.w) + (1.f - g3) * bf2f(cv4.w);
        }
        *(float4*)&out[(size_t)(row0 + m) * H_ + col0 + cl] = o;
    }
}

// ---------------------------------------------------------------------------
extern "C" void kernel_launch(void* const* d_in, const int* in_sizes, int n_in,
                              void* d_out, int out_size, void* d_ws, size_t ws_size,
                              hipStream_t stream)
{
    const float* x   = (const float*)d_in[0];
    const int*   adj = (const int*)  d_in[1];
    const float* Wq  = (const float*)d_in[2];
    const float* Wk  = (const float*)d_in[3];
    const float* Wv  = (const float*)d_in[4];
    const float* Wg  = (const float*)d_in[5];
    const float* bg  = (const float*)d_in[6];
    float* out = (float*)d_out;

    unsigned short* xb  = (unsigned short*)d_ws;                      // 8 MB
    unsigned short* wqb = xb  + (size_t)M_ * H_;                      // 512 KB
    unsigned short* wkb = wqb + (size_t)H_ * H_;
    unsigned short* wvb = wkb + (size_t)H_ * H_;
    unsigned short* wgb = wvb + (size_t)H_ * H_;                      // 1 MB
    unsigned short* qk  = wgb + (size_t)H_ * 2 * H_;                  // 16 MB
    unsigned short* vt  = qk  + (size_t)M_ * 2 * H_;                  // 8 MB
    unsigned short* cmb = vt  + (size_t)M_ * H_;                      // 8 MB
    unsigned long long* mb = (unsigned long long*)(cmb + (size_t)M_ * H_);  // 1 MB

    prep_k<<<5376 + 8192, 256, 0, stream>>>(x, Wq, Wk, Wv, Wg, adj,
                                            xb, wqb, wkb, wvb, wgb, mb);

    proj_k<<<dim3(M_ / 128, 12), 256, 0, stream>>>(xb, wqb, wkb, wvb, qk, vt);

    attn_k<<<B_ * NH_ * (N_ / 128), 512, 0, stream>>>(qk, vt, mb, cmb);

    gate_k<<<dim3(M_ / 128, H_ / 64), 256, 0, stream>>>(cmb, xb, wgb, bg, out);
}